// Round 1
// baseline (552.577 us; speedup 1.0000x reference)
//
#include <hip/hip_runtime.h>

// Scatter-mean voxel pooling: N=1e6 points, C=64 channels, K=64 grid.
// out[cell, c] = mean over points in cell of point_feat[p, c].
//
// Strategy: one 64-lane wave per point; lane == channel. Coalesced 256B
// feature load per point, 64 contiguous fp32 atomicAdds into the sum buffer
// (d_out), lane 0 bumps the per-cell count (d_ws). Second pass divides.

#define KGRID 64
#define NCH   64
#define NCELLS (KGRID * KGRID * KGRID)

__global__ __launch_bounds__(256) void scatter_kernel(
    const float* __restrict__ feat,
    const float* __restrict__ pts,
    float* __restrict__ sums,
    float* __restrict__ counts,
    int n)
{
    const int lane   = threadIdx.x & 63;
    const int wavesPerBlock = blockDim.x >> 6;
    const int wave   = blockIdx.x * wavesPerBlock + (threadIdx.x >> 6);
    const int nwaves = gridDim.x * wavesPerBlock;

    for (int p = wave; p < n; p += nwaves) {
        // All 64 lanes read the same 3 floats -> HW broadcast, cheap.
        float px = pts[3 * p + 0];
        float py = pts[3 * p + 1];
        float pz = pts[3 * p + 2];
        int ix = min(max((int)floorf((px + 1.0f) * 32.0f), 0), KGRID - 1);
        int iy = min(max((int)floorf((py + 1.0f) * 32.0f), 0), KGRID - 1);
        int iz = min(max((int)floorf((pz + 1.0f) * 32.0f), 0), KGRID - 1);
        int cell = (ix << 12) | (iy << 6) | iz;

        float f = feat[(size_t)p * NCH + lane];
        atomicAdd(&sums[(size_t)cell * NCH + lane], f);
        if (lane == 0) atomicAdd(&counts[cell], 1.0f);
    }
}

__global__ __launch_bounds__(256) void finalize_kernel(
    float* __restrict__ out,
    const float* __restrict__ counts)
{
    // One thread per float4; 16 float4 per cell (C=64).
    size_t i = (size_t)blockIdx.x * blockDim.x + threadIdx.x;
    float4* o4 = (float4*)out;
    int cell = (int)(i >> 4);
    float cnt = counts[cell];
    float inv = (cnt > 0.0f) ? (1.0f / cnt) : 1.0f;
    float4 v = o4[i];
    v.x *= inv; v.y *= inv; v.z *= inv; v.w *= inv;
    o4[i] = v;
}

extern "C" void kernel_launch(void* const* d_in, const int* in_sizes, int n_in,
                              void* d_out, int out_size, void* d_ws, size_t ws_size,
                              hipStream_t stream)
{
    const float* feat = (const float*)d_in[0];   // (N, 64) fp32
    const float* pts  = (const float*)d_in[1];   // (N, 3)  fp32
    // d_in[2] is k (== 64), compile-time constant here.
    float* out    = (float*)d_out;               // (64,64,64,64) fp32 sums -> means
    float* counts = (float*)d_ws;                // 64^3 fp32 counts

    const int n = in_sizes[0] / NCH;             // number of points

    // Harness poisons d_out / d_ws to 0xAA before every timed call.
    hipMemsetAsync(out,    0, (size_t)out_size * sizeof(float), stream);
    hipMemsetAsync(counts, 0, (size_t)NCELLS   * sizeof(float), stream);

    // Scatter: 16384 blocks x 256 threads = 64Ki waves, ~15 points each.
    scatter_kernel<<<16384, 256, 0, stream>>>(feat, pts, out, counts, n);

    // Finalize: NCELLS*NCH/4 float4 elements.
    const int n4 = NCELLS * NCH / 4;             // 4,194,304
    finalize_kernel<<<n4 / 256, 256, 0, stream>>>(out, counts);
}

// Round 2
// 551.241 us; speedup vs baseline: 1.0024x; 1.0024x over previous
//
#include <hip/hip_runtime.h>

// Scatter-mean voxel pooling via counting sort — no fp32 atomics.
// N=1e6 points, C=64 channels, K=64 grid (262144 cells).
//
// Pipeline:
//   0. memset counts (1 MB)
//   1. compute_cells : cellid[p], histogram counts[] (int atomics)
//   2. scan_reduce / scan_blocksums / scan_write : exclusive prefix sum -> offsets[]
//   3. build_order   : slot = atomicAdd(offsets[cell]) ; order[slot] = p
//                      (afterwards offsets[cell] == end of cell's range)
//   4. reduce_cells  : one wave per cell, lane==channel; gather feature rows
//                      (coalesced 256B loads), divide by count, write out.

#define KGRID  64
#define NCH    64
#define NCELLS (KGRID * KGRID * KGRID)   // 262144
#define SCAN_CHUNK  1024
#define SCAN_BLOCKS (NCELLS / SCAN_CHUNK) // 256

__global__ __launch_bounds__(256) void compute_cells(
    const float* __restrict__ pts,
    int* __restrict__ cellid,
    int* __restrict__ counts,
    int n)
{
    int p = blockIdx.x * blockDim.x + threadIdx.x;
    if (p >= n) return;
    float px = pts[3 * p + 0];
    float py = pts[3 * p + 1];
    float pz = pts[3 * p + 2];
    int ix = min(max((int)floorf((px + 1.0f) * 32.0f), 0), KGRID - 1);
    int iy = min(max((int)floorf((py + 1.0f) * 32.0f), 0), KGRID - 1);
    int iz = min(max((int)floorf((pz + 1.0f) * 32.0f), 0), KGRID - 1);
    int cell = (ix << 12) | (iy << 6) | iz;
    cellid[p] = cell;
    atomicAdd(&counts[cell], 1);
}

// Per-chunk sums (1024 ints per block).
__global__ __launch_bounds__(256) void scan_reduce(
    const int* __restrict__ counts, int* __restrict__ blocksums)
{
    __shared__ int s[256];
    int b = blockIdx.x, t = threadIdx.x;
    const int4* c4 = (const int4*)(counts + b * SCAN_CHUNK);
    int4 v = c4[t];
    s[t] = v.x + v.y + v.z + v.w;
    __syncthreads();
    for (int off = 128; off > 0; off >>= 1) {
        if (t < off) s[t] += s[t + off];
        __syncthreads();
    }
    if (t == 0) blocksums[b] = s[0];
}

// Exclusive scan of the 256 block sums (single block).
__global__ __launch_bounds__(256) void scan_blocksums(
    const int* __restrict__ blocksums, int* __restrict__ blockbase)
{
    __shared__ int s[256];
    int t = threadIdx.x;
    int v = blocksums[t];
    s[t] = v;
    __syncthreads();
    for (int off = 1; off < 256; off <<= 1) {
        int x = (t >= off) ? s[t - off] : 0;
        __syncthreads();
        s[t] += x;
        __syncthreads();
    }
    blockbase[t] = s[t] - v;   // exclusive
}

// Chunk-local exclusive scan + block base -> final offsets.
__global__ __launch_bounds__(256) void scan_write(
    const int* __restrict__ counts,
    const int* __restrict__ blockbase,
    int* __restrict__ offsets)
{
    __shared__ int s[256];
    int b = blockIdx.x, t = threadIdx.x;
    const int4* c4 = (const int4*)(counts + b * SCAN_CHUNK);
    int4 v = c4[t];
    int tsum = v.x + v.y + v.z + v.w;
    s[t] = tsum;
    __syncthreads();
    for (int off = 1; off < 256; off <<= 1) {
        int x = (t >= off) ? s[t - off] : 0;
        __syncthreads();
        s[t] += x;
        __syncthreads();
    }
    int base = blockbase[b] + (s[t] - tsum);  // exclusive across chunk
    int4 o;
    o.x = base;
    o.y = base + v.x;
    o.z = base + v.x + v.y;
    o.w = base + v.x + v.y + v.z;
    ((int4*)(offsets + b * SCAN_CHUNK))[t] = o;
}

__global__ __launch_bounds__(256) void build_order(
    const int* __restrict__ cellid,
    int* __restrict__ offsets,
    int* __restrict__ order,
    int n)
{
    int p = blockIdx.x * blockDim.x + threadIdx.x;
    if (p >= n) return;
    int cell = cellid[p];
    int slot = atomicAdd(&offsets[cell], 1);
    order[slot] = p;
}

// One wave per cell; lane == channel. After build_order, offsets[cell] is the
// END of the cell's slot range; counts[cell] is its length.
__global__ __launch_bounds__(256) void reduce_cells(
    const float* __restrict__ feat,
    const int* __restrict__ order,
    const int* __restrict__ offsets,
    const int* __restrict__ counts,
    float* __restrict__ out)
{
    int lane = threadIdx.x & 63;
    int wave = (int)((blockIdx.x * blockDim.x + threadIdx.x) >> 6);
    if (wave >= NCELLS) return;
    int cell = wave;
    int len = counts[cell];
    int end = offsets[cell];
    int start = end - len;

    float acc = 0.0f;
    int j = start;
    // Batch of 4: independent order loads, then independent feature loads.
    while (j + 4 <= end) {
        int p0 = order[j + 0];
        int p1 = order[j + 1];
        int p2 = order[j + 2];
        int p3 = order[j + 3];
        acc += feat[(size_t)p0 * NCH + lane];
        acc += feat[(size_t)p1 * NCH + lane];
        acc += feat[(size_t)p2 * NCH + lane];
        acc += feat[(size_t)p3 * NCH + lane];
        j += 4;
    }
    for (; j < end; ++j) {
        int p = order[j];
        acc += feat[(size_t)p * NCH + lane];
    }
    float inv = (len > 0) ? (1.0f / (float)len) : 0.0f;
    out[(size_t)cell * NCH + lane] = acc * inv;
}

extern "C" void kernel_launch(void* const* d_in, const int* in_sizes, int n_in,
                              void* d_out, int out_size, void* d_ws, size_t ws_size,
                              hipStream_t stream)
{
    const float* feat = (const float*)d_in[0];   // (N, 64) fp32
    const float* pts  = (const float*)d_in[1];   // (N, 3)  fp32
    float* out = (float*)d_out;                  // (64,64,64,64) fp32

    const int n = in_sizes[0] / NCH;

    // Workspace layout (ints): counts | offsets | cellid | order | blocksums | blockbase
    int* counts    = (int*)d_ws;                 // NCELLS
    int* offsets   = counts + NCELLS;            // NCELLS
    int* cellid    = offsets + NCELLS;           // n
    int* order     = cellid + n;                 // n
    int* blocksums = order + n;                  // SCAN_BLOCKS
    int* blockbase = blocksums + SCAN_BLOCKS;    // SCAN_BLOCKS

    hipMemsetAsync(counts, 0, (size_t)NCELLS * sizeof(int), stream);

    int pblocks = (n + 255) / 256;
    compute_cells<<<pblocks, 256, 0, stream>>>(pts, cellid, counts, n);

    scan_reduce   <<<SCAN_BLOCKS, 256, 0, stream>>>(counts, blocksums);
    scan_blocksums<<<1,           256, 0, stream>>>(blocksums, blockbase);
    scan_write    <<<SCAN_BLOCKS, 256, 0, stream>>>(counts, blockbase, offsets);

    build_order<<<pblocks, 256, 0, stream>>>(cellid, offsets, order, n);

    // 262144 waves = 65536 blocks of 4 waves.
    reduce_cells<<<NCELLS / 4, 256, 0, stream>>>(feat, order, offsets, counts, out);
}

// Round 3
// 545.296 us; speedup vs baseline: 1.0134x; 1.0109x over previous
//
#include <hip/hip_runtime.h>

// Scatter-mean voxel pooling via counting sort — no fp32 atomics.
// N=1e6 points, C=64 channels, K=64 grid (262144 cells).
//
// Round-3 change: reduce_cells re-mapped so one wave gathers 4 point-rows
// per load instruction (16 lanes x float4 per row = 256B/row, 1KB/instr)
// instead of 1 row (64 lanes x 4B). Latency-bound gather -> 4x bytes in
// flight per outstanding request. Cross-group sum via 2 xor-shuffles.

#define KGRID  64
#define NCH    64
#define NCELLS (KGRID * KGRID * KGRID)   // 262144
#define SCAN_CHUNK  1024
#define SCAN_BLOCKS (NCELLS / SCAN_CHUNK) // 256

__device__ __forceinline__ int cell_of(float px, float py, float pz) {
    int ix = min(max((int)floorf((px + 1.0f) * 32.0f), 0), KGRID - 1);
    int iy = min(max((int)floorf((py + 1.0f) * 32.0f), 0), KGRID - 1);
    int iz = min(max((int)floorf((pz + 1.0f) * 32.0f), 0), KGRID - 1);
    return (ix << 12) | (iy << 6) | iz;
}

// 4 points per thread: 3 float4 loads = 12 floats = 4 points.
__global__ __launch_bounds__(256) void compute_cells(
    const float* __restrict__ pts,
    int* __restrict__ cellid,
    int* __restrict__ counts,
    int n)
{
    int t = blockIdx.x * blockDim.x + threadIdx.x;
    int p0 = t * 4;
    if (p0 >= n) return;
    if (p0 + 4 <= n) {
        const float4* p4 = (const float4*)(pts + (size_t)p0 * 3);
        float4 a = p4[0], b = p4[1], c = p4[2];
        int4 cid;
        cid.x = cell_of(a.x, a.y, a.z);
        cid.y = cell_of(a.w, b.x, b.y);
        cid.z = cell_of(b.z, b.w, c.x);
        cid.w = cell_of(c.y, c.z, c.w);
        *(int4*)(cellid + p0) = cid;
        atomicAdd(&counts[cid.x], 1);
        atomicAdd(&counts[cid.y], 1);
        atomicAdd(&counts[cid.z], 1);
        atomicAdd(&counts[cid.w], 1);
    } else {
        for (int p = p0; p < n; ++p) {
            int c = cell_of(pts[3*p], pts[3*p+1], pts[3*p+2]);
            cellid[p] = c;
            atomicAdd(&counts[c], 1);
        }
    }
}

// Per-chunk sums (1024 ints per block).
__global__ __launch_bounds__(256) void scan_reduce(
    const int* __restrict__ counts, int* __restrict__ blocksums)
{
    __shared__ int s[256];
    int b = blockIdx.x, t = threadIdx.x;
    const int4* c4 = (const int4*)(counts + b * SCAN_CHUNK);
    int4 v = c4[t];
    s[t] = v.x + v.y + v.z + v.w;
    __syncthreads();
    for (int off = 128; off > 0; off >>= 1) {
        if (t < off) s[t] += s[t + off];
        __syncthreads();
    }
    if (t == 0) blocksums[b] = s[0];
}

// Exclusive scan of the 256 block sums (single block).
__global__ __launch_bounds__(256) void scan_blocksums(
    const int* __restrict__ blocksums, int* __restrict__ blockbase)
{
    __shared__ int s[256];
    int t = threadIdx.x;
    int v = blocksums[t];
    s[t] = v;
    __syncthreads();
    for (int off = 1; off < 256; off <<= 1) {
        int x = (t >= off) ? s[t - off] : 0;
        __syncthreads();
        s[t] += x;
        __syncthreads();
    }
    blockbase[t] = s[t] - v;   // exclusive
}

// Chunk-local exclusive scan + block base -> final offsets.
__global__ __launch_bounds__(256) void scan_write(
    const int* __restrict__ counts,
    const int* __restrict__ blockbase,
    int* __restrict__ offsets)
{
    __shared__ int s[256];
    int b = blockIdx.x, t = threadIdx.x;
    const int4* c4 = (const int4*)(counts + b * SCAN_CHUNK);
    int4 v = c4[t];
    int tsum = v.x + v.y + v.z + v.w;
    s[t] = tsum;
    __syncthreads();
    for (int off = 1; off < 256; off <<= 1) {
        int x = (t >= off) ? s[t - off] : 0;
        __syncthreads();
        s[t] += x;
        __syncthreads();
    }
    int base = blockbase[b] + (s[t] - tsum);  // exclusive across chunk
    int4 o;
    o.x = base;
    o.y = base + v.x;
    o.z = base + v.x + v.y;
    o.w = base + v.x + v.y + v.z;
    ((int4*)(offsets + b * SCAN_CHUNK))[t] = o;
}

// 4 points per thread.
__global__ __launch_bounds__(256) void build_order(
    const int* __restrict__ cellid,
    int* __restrict__ offsets,
    int* __restrict__ order,
    int n)
{
    int t = blockIdx.x * blockDim.x + threadIdx.x;
    int p0 = t * 4;
    if (p0 >= n) return;
    if (p0 + 4 <= n) {
        int4 cid = *(const int4*)(cellid + p0);
        int s0 = atomicAdd(&offsets[cid.x], 1);
        int s1 = atomicAdd(&offsets[cid.y], 1);
        int s2 = atomicAdd(&offsets[cid.z], 1);
        int s3 = atomicAdd(&offsets[cid.w], 1);
        order[s0] = p0 + 0;
        order[s1] = p0 + 1;
        order[s2] = p0 + 2;
        order[s3] = p0 + 3;
    } else {
        for (int p = p0; p < n; ++p) {
            int slot = atomicAdd(&offsets[cellid[p]], 1);
            order[slot] = p;
        }
    }
}

// One wave per cell. Lane mapping: grp = lane>>4 picks point j+grp,
// ch4 = lane&15 picks the float4 chunk of that point's 64-ch row.
// Each feat load instruction moves 4 rows = 1 KB per wave.
__global__ __launch_bounds__(256) void reduce_cells(
    const float4* __restrict__ feat4,
    const int* __restrict__ order,
    const int* __restrict__ offsets,   // == end of each cell's range
    const int* __restrict__ counts,    // == length
    float4* __restrict__ out4)
{
    int lane = threadIdx.x & 63;
    int wave = (int)((blockIdx.x * blockDim.x + threadIdx.x) >> 6);
    if (wave >= NCELLS) return;
    int cell = wave;
    int len = counts[cell];
    int end = offsets[cell];
    int start = end - len;
    int grp = lane >> 4;
    int ch4 = lane & 15;

    float4 acc = make_float4(0.f, 0.f, 0.f, 0.f);
    if (len > 0) {
        for (int j = start; j < end; j += 4) {
            int jj = j + grp;
            int p = order[(jj < end) ? jj : (end - 1)];
            float4 f = feat4[(size_t)p * (NCH / 4) + ch4];
            if (jj < end) {
                acc.x += f.x; acc.y += f.y; acc.z += f.z; acc.w += f.w;
            }
        }
        // Sum the 4 lane-groups (same ch4, different points).
        acc.x += __shfl_xor(acc.x, 16, 64);
        acc.y += __shfl_xor(acc.y, 16, 64);
        acc.z += __shfl_xor(acc.z, 16, 64);
        acc.w += __shfl_xor(acc.w, 16, 64);
        acc.x += __shfl_xor(acc.x, 32, 64);
        acc.y += __shfl_xor(acc.y, 32, 64);
        acc.z += __shfl_xor(acc.z, 32, 64);
        acc.w += __shfl_xor(acc.w, 32, 64);
        float inv = 1.0f / (float)len;
        acc.x *= inv; acc.y *= inv; acc.z *= inv; acc.w *= inv;
    }
    if (lane < 16) out4[(size_t)cell * (NCH / 4) + ch4] = acc;
}

extern "C" void kernel_launch(void* const* d_in, const int* in_sizes, int n_in,
                              void* d_out, int out_size, void* d_ws, size_t ws_size,
                              hipStream_t stream)
{
    const float* feat = (const float*)d_in[0];   // (N, 64) fp32
    const float* pts  = (const float*)d_in[1];   // (N, 3)  fp32
    float* out = (float*)d_out;                  // (64,64,64,64) fp32

    const int n = in_sizes[0] / NCH;

    // Workspace layout (ints): counts | offsets | cellid | order | blocksums | blockbase
    int* counts    = (int*)d_ws;                 // NCELLS
    int* offsets   = counts + NCELLS;            // NCELLS
    int* cellid    = offsets + NCELLS;           // n
    int* order     = cellid + n;                 // n
    int* blocksums = order + n;                  // SCAN_BLOCKS
    int* blockbase = blocksums + SCAN_BLOCKS;    // SCAN_BLOCKS

    hipMemsetAsync(counts, 0, (size_t)NCELLS * sizeof(int), stream);

    int t4 = (n + 3) / 4;
    int pblocks4 = (t4 + 255) / 256;
    compute_cells<<<pblocks4, 256, 0, stream>>>(pts, cellid, counts, n);

    scan_reduce   <<<SCAN_BLOCKS, 256, 0, stream>>>(counts, blocksums);
    scan_blocksums<<<1,           256, 0, stream>>>(blocksums, blockbase);
    scan_write    <<<SCAN_BLOCKS, 256, 0, stream>>>(counts, blockbase, offsets);

    build_order<<<pblocks4, 256, 0, stream>>>(cellid, offsets, order, n);

    // 262144 waves = 65536 blocks of 4 waves.
    reduce_cells<<<NCELLS / 4, 256, 0, stream>>>(
        (const float4*)feat, order, offsets, counts, (float4*)out);
}